// Round 2
// baseline (1201.115 us; speedup 1.0000x reference)
//
#include <hip/hip_runtime.h>
#include <stdint.h>
#include <stddef.h>

#define N_ATOMS 50000
#define N_EDGES 524288
#define FA 133
#define FB 14
#define H 128
#define DEPTH 3
#define KI 160   /* 147 padded to multiple of 32 */
#define KU 256
#define KR 128

typedef __attribute__((ext_vector_type(8))) __bf16 bf16x8;
typedef __attribute__((ext_vector_type(4))) float f32x4;

__device__ __forceinline__ uint16_t f2bf(float f) {
    uint32_t u = __builtin_bit_cast(uint32_t, f);
    return (uint16_t)((u + 0x7FFFu + ((u >> 16) & 1u)) >> 16);
}
__device__ __forceinline__ float bf2f(uint16_t h) {
    return __builtin_bit_cast(float, (uint32_t)h << 16);
}

// ---------------- weight conversion (fp32 -> bf16, W_init padded 147->160) --
__global__ void k_weights(const float* __restrict__ Wi_f,
                          const float* __restrict__ Wu_f,
                          const float* __restrict__ Wr_f,
                          uint16_t* __restrict__ Wi,
                          uint16_t* __restrict__ Wu,
                          uint16_t* __restrict__ Wr) {
    int i = blockIdx.x * 256 + threadIdx.x;
    if (i < H * KI) {
        int o = i / KI, k = i - o * KI;
        float v = (k < FA + FB) ? Wi_f[o * (FA + FB) + k] : 0.f;
        Wi[i] = f2bf(v);
    } else if (i < H * KI + H * KU) {
        int j = i - H * KI;
        Wu[j] = f2bf(Wu_f[j]);
    } else if (i < H * KI + H * KU + H * KR) {
        int j = i - H * KI - H * KU;
        Wr[j] = f2bf(Wr_f[j]);
    }
}

// ---------------- CSR build ------------------------------------------------
__global__ void k_hist(const int* __restrict__ dstv, int* __restrict__ counts) {
    int e = blockIdx.x * 256 + threadIdx.x;
    if (e < N_EDGES) atomicAdd(&counts[dstv[e]], 1);
}

__global__ void k_scan(const int* __restrict__ counts,
                       int* __restrict__ row_ptr, int* __restrict__ nxt) {
    __shared__ int s[1024];
    const int t = threadIdx.x;
    const int PER = (N_ATOMS + 1023) / 1024;  // 49
    const int base = t * PER;
    int local = 0;
    for (int j = 0; j < PER; ++j) {
        int i = base + j;
        if (i < N_ATOMS) local += counts[i];
    }
    s[t] = local;
    __syncthreads();
    for (int off = 1; off < 1024; off <<= 1) {
        int u = (t >= off) ? s[t - off] : 0;
        __syncthreads();
        s[t] += u;
        __syncthreads();
    }
    int run = s[t] - local;  // exclusive prefix of this thread's range
    for (int j = 0; j < PER; ++j) {
        int i = base + j;
        if (i < N_ATOMS) {
            row_ptr[i] = run;
            nxt[i] = run;
            run += counts[i];
        }
    }
    if (t == 1023) row_ptr[N_ATOMS] = run;
}

__global__ void k_scatter(const int* __restrict__ dstv, int* __restrict__ nxt,
                          int* __restrict__ edge_slot) {
    int e = blockIdx.x * 256 + threadIdx.x;
    if (e < N_EDGES) {
        int pos = atomicAdd(&nxt[dstv[e]], 1);
        edge_slot[pos] = e;
    }
}

// ---------------- segment sum: sum_in[a,:] = sum over edges with dst==a ----
__global__ void k_segsum(const uint16_t* __restrict__ h,
                         const int* __restrict__ row_ptr,
                         const int* __restrict__ edge_slot,
                         float* __restrict__ sum) {
    const int w = threadIdx.x >> 6;
    const int lane = threadIdx.x & 63;
    const int a = blockIdx.x * 4 + w;
    if (a >= N_ATOMS) return;
    const int s0 = row_ptr[a], s1 = row_ptr[a + 1];
    float acc0 = 0.f, acc1 = 0.f;
    for (int idx = s0; idx < s1; ++idx) {
        int eid = edge_slot[idx];
        uint32_t u = *(const uint32_t*)(h + (size_t)eid * H + lane * 2);
        acc0 += bf2f((uint16_t)(u & 0xFFFFu));
        acc1 += bf2f((uint16_t)(u >> 16));
    }
    float2* o = (float2*)(sum + (size_t)a * H + lane * 2);
    *o = make_float2(acc0, acc1);
}

// ---------------- init GEMM: h0 = relu([atom[src], bond] @ Wi^T + b) -------
__global__ __launch_bounds__(256, 3) void k_init(
    const float* __restrict__ atom, const float* __restrict__ bond,
    const int* __restrict__ srcv, const uint16_t* __restrict__ Wi,
    const float* __restrict__ b_init, uint16_t* __restrict__ h_out) {
    __shared__ __align__(16) uint16_t A[128 * 168];  // [128][160] padded +8
    __shared__ int src_lds[128];
    const int t = threadIdx.x;
    const int base = blockIdx.x * 128;
    if (t < 128) src_lds[t] = srcv[base + t];
    __syncthreads();
    for (int j = 0; j < 80; ++j) {
        int idx = j * 256 + t;
        int r = idx / KI;
        int k = idx - r * KI;
        float v = 0.f;
        if (k < FA) v = atom[(size_t)src_lds[r] * FA + k];
        else if (k < FA + FB) v = bond[(size_t)(base + r) * FB + (k - FA)];
        A[r * 168 + k] = f2bf(v);
    }
    __syncthreads();
    const int w = t >> 6, lane = t & 63;
    const int wm = w >> 1, wn = w & 1;
    const int l15 = lane & 15, q = lane >> 4;
    f32x4 acc[4][4];
    const f32x4 z = {0.f, 0.f, 0.f, 0.f};
    for (int i = 0; i < 4; ++i)
        for (int jj = 0; jj < 4; ++jj) acc[i][jj] = z;
#pragma unroll
    for (int ks = 0; ks < 5; ++ks) {
        const int kk = ks * 32 + q * 8;
        bf16x8 a[4], b[4];
#pragma unroll
        for (int i = 0; i < 4; ++i)
            a[i] = *(const bf16x8*)&A[(wm * 64 + i * 16 + l15) * 168 + kk];
#pragma unroll
        for (int jj = 0; jj < 4; ++jj)
            b[jj] = *(const bf16x8*)&Wi[(wn * 64 + jj * 16 + l15) * KI + kk];
#pragma unroll
        for (int i = 0; i < 4; ++i)
#pragma unroll
            for (int jj = 0; jj < 4; ++jj)
                acc[i][jj] = __builtin_amdgcn_mfma_f32_16x16x32_bf16(a[i], b[jj], acc[i][jj], 0, 0, 0);
    }
    __syncthreads();
#pragma unroll
    for (int jj = 0; jj < 4; ++jj) {
        const int col = wn * 64 + jj * 16 + l15;
        const float bias = b_init[col];
#pragma unroll
        for (int i = 0; i < 4; ++i)
#pragma unroll
            for (int r = 0; r < 4; ++r) {
                const int row = wm * 64 + i * 16 + q * 4 + r;
                float v = acc[i][jj][r] + bias;
                A[row * 136 + col] = f2bf(v > 0.f ? v : 0.f);
            }
    }
    __syncthreads();
    for (int j = 0; j < 8; ++j) {
        int c = j * 256 + t;
        int row = c >> 4, kc = c & 15;
        *(bf16x8*)(h_out + (size_t)(base + row) * H + kc * 8) =
            *(const bf16x8*)&A[row * 136 + kc * 8];
    }
}

// ---- update GEMM (IN-PLACE safe: rev=e^1 stays in this block's tile) ------
// h' = relu([h, sum[src]-h[e^1]] @ Wu^T + b); all h reads precede h writes
// within the block and no other block touches these 128 rows.
__global__ __launch_bounds__(256, 3) void k_update(
    uint16_t* __restrict__ h_io, const float* __restrict__ sum,
    const int* __restrict__ srcv, const uint16_t* __restrict__ Wu,
    const float* __restrict__ b_upd) {
    __shared__ __align__(16) uint16_t A[128 * 136];  // [128][128] padded +8
    __shared__ int src_lds[128];
    const int t = threadIdx.x;
    const int base = blockIdx.x * 128;
    if (t < 128) src_lds[t] = srcv[base + t];
    const int w = t >> 6, lane = t & 63;
    const int wm = w >> 1, wn = w & 1;
    const int l15 = lane & 15, q = lane >> 4;
    f32x4 acc[4][4];
    const f32x4 z = {0.f, 0.f, 0.f, 0.f};
    for (int i = 0; i < 4; ++i)
        for (int jj = 0; jj < 4; ++jj) acc[i][jj] = z;
    // phase 0: k = 0..127 is h[e]
    for (int j = 0; j < 8; ++j) {
        int c = j * 256 + t;
        int row = c >> 4, kc = c & 15;
        *(bf16x8*)&A[row * 136 + kc * 8] =
            *(const bf16x8*)(h_io + (size_t)(base + row) * H + kc * 8);
    }
    __syncthreads();
#pragma unroll
    for (int ks = 0; ks < 4; ++ks) {
        const int kk = ks * 32 + q * 8;
        bf16x8 a[4], b[4];
#pragma unroll
        for (int i = 0; i < 4; ++i)
            a[i] = *(const bf16x8*)&A[(wm * 64 + i * 16 + l15) * 136 + kk];
#pragma unroll
        for (int jj = 0; jj < 4; ++jj)
            b[jj] = *(const bf16x8*)&Wu[(wn * 64 + jj * 16 + l15) * KU + kk];
#pragma unroll
        for (int i = 0; i < 4; ++i)
#pragma unroll
            for (int jj = 0; jj < 4; ++jj)
                acc[i][jj] = __builtin_amdgcn_mfma_f32_16x16x32_bf16(a[i], b[jj], acc[i][jj], 0, 0, 0);
    }
    __syncthreads();
    // phase 1: k = 128..255 is m = sum[src[e]] - h[e^1]
    for (int j = 0; j < 16; ++j) {
        int c4 = j * 256 + t;
        int row = c4 >> 5, cc = (c4 & 31) * 4;
        float4 s4 = *(const float4*)(sum + (size_t)src_lds[row] * H + cc);
        uint2 hv = *(const uint2*)(h_io + (size_t)(base + (row ^ 1)) * H + cc);
        float m0 = s4.x - bf2f((uint16_t)(hv.x & 0xFFFFu));
        float m1 = s4.y - bf2f((uint16_t)(hv.x >> 16));
        float m2 = s4.z - bf2f((uint16_t)(hv.y & 0xFFFFu));
        float m3 = s4.w - bf2f((uint16_t)(hv.y >> 16));
        uint2 p;
        p.x = (uint32_t)f2bf(m0) | ((uint32_t)f2bf(m1) << 16);
        p.y = (uint32_t)f2bf(m2) | ((uint32_t)f2bf(m3) << 16);
        *(uint2*)&A[row * 136 + cc] = p;
    }
    __syncthreads();
#pragma unroll
    for (int ks = 0; ks < 4; ++ks) {
        const int kk = ks * 32 + q * 8;
        bf16x8 a[4], b[4];
#pragma unroll
        for (int i = 0; i < 4; ++i)
            a[i] = *(const bf16x8*)&A[(wm * 64 + i * 16 + l15) * 136 + kk];
#pragma unroll
        for (int jj = 0; jj < 4; ++jj)
            b[jj] = *(const bf16x8*)&Wu[(wn * 64 + jj * 16 + l15) * KU + 128 + kk];
#pragma unroll
        for (int i = 0; i < 4; ++i)
#pragma unroll
            for (int jj = 0; jj < 4; ++jj)
                acc[i][jj] = __builtin_amdgcn_mfma_f32_16x16x32_bf16(a[i], b[jj], acc[i][jj], 0, 0, 0);
    }
    __syncthreads();
#pragma unroll
    for (int jj = 0; jj < 4; ++jj) {
        const int col = wn * 64 + jj * 16 + l15;
        const float bias = b_upd[col];
#pragma unroll
        for (int i = 0; i < 4; ++i)
#pragma unroll
            for (int r = 0; r < 4; ++r) {
                const int row = wm * 64 + i * 16 + q * 4 + r;
                float v = acc[i][jj][r] + bias;
                A[row * 136 + col] = f2bf(v > 0.f ? v : 0.f);
            }
    }
    __syncthreads();
    for (int j = 0; j < 8; ++j) {
        int c = j * 256 + t;
        int row = c >> 4, kc = c & 15;
        *(bf16x8*)(h_io + (size_t)(base + row) * H + kc * 8) =
            *(const bf16x8*)&A[row * 136 + kc * 8];
    }
}

// ---------------- readout: out += colsum(relu(sum @ Wr^T + b)) -------------
__global__ __launch_bounds__(256, 3) void k_readout(
    const float* __restrict__ sum, const uint16_t* __restrict__ Wr,
    const float* __restrict__ b_read, float* __restrict__ out) {
    __shared__ __align__(16) uint16_t A[128 * 136];
    __shared__ float col_lds[128];
    const int t = threadIdx.x;
    const int base = blockIdx.x * 128;
    if (t < 128) col_lds[t] = 0.f;
    for (int j = 0; j < 16; ++j) {
        int c4 = j * 256 + t;
        int row = c4 >> 5, cc = (c4 & 31) * 4;
        int a_idx = base + row;
        float4 s4 = make_float4(0.f, 0.f, 0.f, 0.f);
        if (a_idx < N_ATOMS) s4 = *(const float4*)(sum + (size_t)a_idx * H + cc);
        uint2 p;
        p.x = (uint32_t)f2bf(s4.x) | ((uint32_t)f2bf(s4.y) << 16);
        p.y = (uint32_t)f2bf(s4.z) | ((uint32_t)f2bf(s4.w) << 16);
        *(uint2*)&A[row * 136 + cc] = p;
    }
    __syncthreads();
    const int w = t >> 6, lane = t & 63;
    const int wm = w >> 1, wn = w & 1;
    const int l15 = lane & 15, q = lane >> 4;
    f32x4 acc[4][4];
    const f32x4 z = {0.f, 0.f, 0.f, 0.f};
    for (int i = 0; i < 4; ++i)
        for (int jj = 0; jj < 4; ++jj) acc[i][jj] = z;
#pragma unroll
    for (int ks = 0; ks < 4; ++ks) {
        const int kk = ks * 32 + q * 8;
        bf16x8 a[4], b[4];
#pragma unroll
        for (int i = 0; i < 4; ++i)
            a[i] = *(const bf16x8*)&A[(wm * 64 + i * 16 + l15) * 136 + kk];
#pragma unroll
        for (int jj = 0; jj < 4; ++jj)
            b[jj] = *(const bf16x8*)&Wr[(wn * 64 + jj * 16 + l15) * KR + kk];
#pragma unroll
        for (int i = 0; i < 4; ++i)
#pragma unroll
            for (int jj = 0; jj < 4; ++jj)
                acc[i][jj] = __builtin_amdgcn_mfma_f32_16x16x32_bf16(a[i], b[jj], acc[i][jj], 0, 0, 0);
    }
#pragma unroll
    for (int jj = 0; jj < 4; ++jj) {
        const int col = wn * 64 + jj * 16 + l15;
        const float bias = b_read[col];
        float s = 0.f;
#pragma unroll
        for (int i = 0; i < 4; ++i)
#pragma unroll
            for (int r = 0; r < 4; ++r) {
                const int a_idx = base + wm * 64 + i * 16 + q * 4 + r;
                if (a_idx < N_ATOMS) {
                    float v = acc[i][jj][r] + bias;
                    s += (v > 0.f) ? v : 0.f;
                }
            }
        atomicAdd(&col_lds[col], s);
    }
    __syncthreads();
    if (t < 128) atomicAdd(&out[t], col_lds[t]);
}

// ---------------- launch ---------------------------------------------------
extern "C" void kernel_launch(void* const* d_in, const int* in_sizes, int n_in,
                              void* d_out, int out_size, void* d_ws, size_t ws_size,
                              hipStream_t stream) {
    (void)in_sizes; (void)n_in; (void)out_size; (void)ws_size;
    const float* atom   = (const float*)d_in[0];
    const float* bond   = (const float*)d_in[1];
    const int* edge_idx = (const int*)d_in[2];
    const float* W_init = (const float*)d_in[3];
    const float* b_init = (const float*)d_in[4];
    const float* W_upd  = (const float*)d_in[5];
    const float* b_upd  = (const float*)d_in[6];
    const float* W_read = (const float*)d_in[7];
    const float* b_read = (const float*)d_in[8];
    float* out = (float*)d_out;

    char* ws = (char*)d_ws;
    // Workspace budget (single h buffer, in-place update): ~163 MB total.
    constexpr size_t SZ_H    = (size_t)N_EDGES * H * 2;            // 134217728
    constexpr size_t OFF_H   = 0;
    constexpr size_t OFF_SUM = OFF_H + SZ_H;
    constexpr size_t OFF_WI  = OFF_SUM + (size_t)N_ATOMS * H * 4;  // 25600000
    constexpr size_t OFF_WU  = OFF_WI + (size_t)H * KI * 2;
    constexpr size_t OFF_WR  = OFF_WU + (size_t)H * KU * 2;
    constexpr size_t OFF_CNT = OFF_WR + (size_t)H * KR * 2;
    constexpr size_t OFF_RP  = OFF_CNT + 200192;                   // N*4 -> 256B
    constexpr size_t OFF_NXT = OFF_RP + 200192;
    constexpr size_t OFF_ES  = OFF_NXT + 200192;

    uint16_t* h    = (uint16_t*)(ws + OFF_H);
    float* sum     = (float*)(ws + OFF_SUM);
    uint16_t* Wi   = (uint16_t*)(ws + OFF_WI);
    uint16_t* Wu   = (uint16_t*)(ws + OFF_WU);
    uint16_t* Wr   = (uint16_t*)(ws + OFF_WR);
    int* counts    = (int*)(ws + OFF_CNT);
    int* row_ptr   = (int*)(ws + OFF_RP);
    int* nxt       = (int*)(ws + OFF_NXT);
    int* edge_slot = (int*)(ws + OFF_ES);

    const int* srcv = edge_idx;
    const int* dstv = edge_idx + N_EDGES;

    hipMemsetAsync(counts, 0, N_ATOMS * sizeof(int), stream);
    hipMemsetAsync(d_out, 0, H * sizeof(float), stream);

    k_weights<<<(H * KI + H * KU + H * KR + 255) / 256, 256, 0, stream>>>(
        W_init, W_upd, W_read, Wi, Wu, Wr);
    k_hist<<<(N_EDGES + 255) / 256, 256, 0, stream>>>(dstv, counts);
    k_scan<<<1, 1024, 0, stream>>>(counts, row_ptr, nxt);
    k_scatter<<<(N_EDGES + 255) / 256, 256, 0, stream>>>(dstv, nxt, edge_slot);

    k_init<<<N_EDGES / 128, 256, 0, stream>>>(atom, bond, srcv, Wi, b_init, h);

    for (int d = 0; d < DEPTH; ++d) {
        k_segsum<<<(N_ATOMS + 3) / 4, 256, 0, stream>>>(h, row_ptr, edge_slot, sum);
        k_update<<<N_EDGES / 128, 256, 0, stream>>>(h, sum, srcv, Wu, b_upd);
    }
    k_segsum<<<(N_ATOMS + 3) / 4, 256, 0, stream>>>(h, row_ptr, edge_slot, sum);
    k_readout<<<(N_ATOMS + 127) / 128, 256, 0, stream>>>(sum, Wr, b_read, out);
}

// Round 3
// 944.616 us; speedup vs baseline: 1.2715x; 1.2715x over previous
//
#include <hip/hip_runtime.h>
#include <stdint.h>
#include <stddef.h>

#define N_ATOMS 50000
#define N_EDGES 524288
#define FA 133
#define FB 14
#define H 128
#define DEPTH 3
#define KI 160   /* 133 padded to multiple of 32 */
#define KB 32    /* 14 padded to 32 */
#define KU 256
#define KR 128

typedef __attribute__((ext_vector_type(8))) __bf16 bf16x8;
typedef __attribute__((ext_vector_type(4))) float f32x4;

__device__ __forceinline__ uint16_t f2bf(float f) {
    uint32_t u = __builtin_bit_cast(uint32_t, f);
    return (uint16_t)((u + 0x7FFFu + ((u >> 16) & 1u)) >> 16);
}
__device__ __forceinline__ float bf2f(uint16_t h) {
    return __builtin_bit_cast(float, (uint32_t)h << 16);
}

// ---- weight conversion: Wa = Wi[:, :133] pad->160, Wb = Wi[:, 133:147] pad->32
__global__ void k_weights(const float* __restrict__ Wi_f,
                          const float* __restrict__ Wu_f,
                          const float* __restrict__ Wr_f,
                          uint16_t* __restrict__ Wa,
                          uint16_t* __restrict__ Wb,
                          uint16_t* __restrict__ Wu,
                          uint16_t* __restrict__ Wr) {
    int i = blockIdx.x * 256 + threadIdx.x;
    if (i < H * KI) {
        int o = i / KI, k = i - o * KI;
        Wa[i] = f2bf((k < FA) ? Wi_f[o * (FA + FB) + k] : 0.f);
    } else if (i < H * KI + H * KB) {
        int j = i - H * KI;
        int o = j >> 5, k = j & 31;
        Wb[j] = f2bf((k < FB) ? Wi_f[o * (FA + FB) + FA + k] : 0.f);
    } else if (i < H * KI + H * KB + H * KU) {
        int j = i - H * KI - H * KB;
        Wu[j] = f2bf(Wu_f[j]);
    } else if (i < H * KI + H * KB + H * KU + H * KR) {
        int j = i - H * KI - H * KB - H * KU;
        Wr[j] = f2bf(Wr_f[j]);
    }
}

// ---------------- CSR build ------------------------------------------------
__global__ void k_hist(const int* __restrict__ dstv, int* __restrict__ counts) {
    int e = blockIdx.x * 256 + threadIdx.x;
    if (e < N_EDGES) atomicAdd(&counts[dstv[e]], 1);
}

__global__ void k_scan(const int* __restrict__ counts,
                       int* __restrict__ row_ptr, int* __restrict__ nxt) {
    __shared__ int s[1024];
    const int t = threadIdx.x;
    const int PER = (N_ATOMS + 1023) / 1024;  // 49
    const int base = t * PER;
    int local = 0;
    for (int j = 0; j < PER; ++j) {
        int i = base + j;
        if (i < N_ATOMS) local += counts[i];
    }
    s[t] = local;
    __syncthreads();
    for (int off = 1; off < 1024; off <<= 1) {
        int u = (t >= off) ? s[t - off] : 0;
        __syncthreads();
        s[t] += u;
        __syncthreads();
    }
    int run = s[t] - local;
    for (int j = 0; j < PER; ++j) {
        int i = base + j;
        if (i < N_ATOMS) {
            row_ptr[i] = run;
            nxt[i] = run;
            run += counts[i];
        }
    }
    if (t == 1023) row_ptr[N_ATOMS] = run;
}

__global__ void k_scatter(const int* __restrict__ dstv, int* __restrict__ nxt,
                          int* __restrict__ edge_slot) {
    int e = blockIdx.x * 256 + threadIdx.x;
    if (e < N_EDGES) {
        int pos = atomicAdd(&nxt[dstv[e]], 1);
        edge_slot[pos] = e;
    }
}

// ---- segment sum (2 edges / wave-iter, prefetched edge ids) ---------------
__global__ void k_segsum(const uint16_t* __restrict__ h,
                         const int* __restrict__ row_ptr,
                         const int* __restrict__ edge_slot,
                         float* __restrict__ sum) {
    const int w = threadIdx.x >> 6;
    const int lane = threadIdx.x & 63;
    const int a = blockIdx.x * 4 + w;
    if (a >= N_ATOMS) return;
    const int s0 = row_ptr[a], s1 = row_ptr[a + 1];
    const int half = lane >> 5, sub = lane & 31;
    float4 acc = make_float4(0.f, 0.f, 0.f, 0.f);
    int p = s0;
    int idx0 = p + half;
    int eid = (idx0 < s1) ? edge_slot[idx0] : -1;
    while (p < s1) {
        const int cur = eid;
        p += 2;
        const int idxn = p + half;
        eid = (idxn < s1) ? edge_slot[idxn] : -1;
        if (cur >= 0) {
            const uint2 u = *(const uint2*)(h + (size_t)cur * H + sub * 4);
            acc.x += bf2f((uint16_t)(u.x & 0xFFFFu));
            acc.y += bf2f((uint16_t)(u.x >> 16));
            acc.z += bf2f((uint16_t)(u.y & 0xFFFFu));
            acc.w += bf2f((uint16_t)(u.y >> 16));
        }
    }
    acc.x += __shfl_down(acc.x, 32);
    acc.y += __shfl_down(acc.y, 32);
    acc.z += __shfl_down(acc.z, 32);
    acc.w += __shfl_down(acc.w, 32);
    if (half == 0)
        *(float4*)(sum + (size_t)a * H + sub * 4) = acc;
}

// ---- P = atom @ Wa^T (dense, gather-free; M=50048 in 391 tiles) -----------
__global__ __launch_bounds__(256, 3) void k_atom_gemm(
    const float* __restrict__ atom, const uint16_t* __restrict__ Wa,
    uint16_t* __restrict__ P) {
    __shared__ __align__(16) uint16_t A[128 * 168];
    const int t = threadIdx.x;
    const int base = blockIdx.x * 128;
    if (t < 128) {
        for (int c = FA; c < KI; ++c) A[t * 168 + c] = 0;
    }
    for (int j = 0; j < 67; ++j) {
        int f = j * 256 + t;
        if (f < 128 * FA) {
            int row = f / FA, col = f - row * FA;
            int a = base + row;
            float v = (a < N_ATOMS) ? atom[(size_t)a * FA + col] : 0.f;
            A[row * 168 + col] = f2bf(v);
        }
    }
    __syncthreads();
    const int w = t >> 6, lane = t & 63;
    const int wm = w >> 1, wn = w & 1;
    const int l15 = lane & 15, q = lane >> 4;
    f32x4 acc[4][4];
    const f32x4 z = {0.f, 0.f, 0.f, 0.f};
    for (int i = 0; i < 4; ++i)
        for (int jj = 0; jj < 4; ++jj) acc[i][jj] = z;
#pragma unroll
    for (int ks = 0; ks < 5; ++ks) {
        const int kk = ks * 32 + q * 8;
        bf16x8 a[4], b[4];
#pragma unroll
        for (int i = 0; i < 4; ++i)
            a[i] = *(const bf16x8*)&A[(wm * 64 + i * 16 + l15) * 168 + kk];
#pragma unroll
        for (int jj = 0; jj < 4; ++jj)
            b[jj] = *(const bf16x8*)&Wa[(wn * 64 + jj * 16 + l15) * KI + kk];
#pragma unroll
        for (int i = 0; i < 4; ++i)
#pragma unroll
            for (int jj = 0; jj < 4; ++jj)
                acc[i][jj] = __builtin_amdgcn_mfma_f32_16x16x32_bf16(a[i], b[jj], acc[i][jj], 0, 0, 0);
    }
    __syncthreads();
#pragma unroll
    for (int jj = 0; jj < 4; ++jj) {
        const int col = wn * 64 + jj * 16 + l15;
#pragma unroll
        for (int i = 0; i < 4; ++i)
#pragma unroll
            for (int r = 0; r < 4; ++r) {
                const int row = wm * 64 + i * 16 + q * 4 + r;
                A[row * 136 + col] = f2bf(acc[i][jj][r]);
            }
    }
    __syncthreads();
    for (int j = 0; j < 8; ++j) {
        int c = j * 256 + t;
        int row = c >> 4, kc = c & 15;
        *(bf16x8*)(P + (size_t)(base + row) * H + kc * 8) =
            *(const bf16x8*)&A[row * 136 + kc * 8];
    }
}

// ---- h0 = relu(P[src] + bond @ Wb^T + b_init) -----------------------------
__global__ __launch_bounds__(256, 3) void k_edge_init(
    const float* __restrict__ bond, const int* __restrict__ srcv,
    const uint16_t* __restrict__ Wb, const uint16_t* __restrict__ P,
    const float* __restrict__ b_init, uint16_t* __restrict__ h_out) {
    __shared__ __align__(16) uint16_t Pl[128 * 136];
    __shared__ __align__(16) uint16_t Bb[128 * 40];
    __shared__ int src_lds[128];
    const int t = threadIdx.x;
    const int base = blockIdx.x * 128;
    if (t < 128) {
        src_lds[t] = srcv[base + t];
        for (int c = FB; c < KB; ++c) Bb[t * 40 + c] = 0;
    }
    for (int j = 0; j < 7; ++j) {
        int f = j * 256 + t;  // f < 1792 always
        int row = f / FB, col = f - row * FB;
        Bb[row * 40 + col] = f2bf(bond[(size_t)(base + row) * FB + col]);
    }
    __syncthreads();
    // vectorized gather of P rows (16 B / lane, 8 independent loads / thread)
    for (int j = 0; j < 8; ++j) {
        int task = j * 256 + t;
        int row = task >> 4, seg = task & 15;
        *(bf16x8*)&Pl[row * 136 + seg * 8] =
            *(const bf16x8*)(P + (size_t)src_lds[row] * H + seg * 8);
    }
    const int w = t >> 6, lane = t & 63;
    const int wm = w >> 1, wn = w & 1;
    const int l15 = lane & 15, q = lane >> 4;
    f32x4 acc[4][4];
    const f32x4 z = {0.f, 0.f, 0.f, 0.f};
    for (int i = 0; i < 4; ++i)
        for (int jj = 0; jj < 4; ++jj) acc[i][jj] = z;
    {
        const int kk = q * 8;
        bf16x8 a[4], b[4];
#pragma unroll
        for (int i = 0; i < 4; ++i)
            a[i] = *(const bf16x8*)&Bb[(wm * 64 + i * 16 + l15) * 40 + kk];
#pragma unroll
        for (int jj = 0; jj < 4; ++jj)
            b[jj] = *(const bf16x8*)&Wb[(wn * 64 + jj * 16 + l15) * KB + kk];
#pragma unroll
        for (int i = 0; i < 4; ++i)
#pragma unroll
            for (int jj = 0; jj < 4; ++jj)
                acc[i][jj] = __builtin_amdgcn_mfma_f32_16x16x32_bf16(a[i], b[jj], acc[i][jj], 0, 0, 0);
    }
    __syncthreads();  // Pl gather complete
    // epilogue: in-place update of Pl (each slot read+written by one lane)
#pragma unroll
    for (int jj = 0; jj < 4; ++jj) {
        const int col = wn * 64 + jj * 16 + l15;
        const float bias = b_init[col];
#pragma unroll
        for (int i = 0; i < 4; ++i)
#pragma unroll
            for (int r = 0; r < 4; ++r) {
                const int row = wm * 64 + i * 16 + q * 4 + r;
                float v = acc[i][jj][r] + bf2f(Pl[row * 136 + col]) + bias;
                Pl[row * 136 + col] = f2bf(v > 0.f ? v : 0.f);
            }
    }
    __syncthreads();
    for (int j = 0; j < 8; ++j) {
        int c = j * 256 + t;
        int row = c >> 4, kc = c & 15;
        *(bf16x8*)(h_out + (size_t)(base + row) * H + kc * 8) =
            *(const bf16x8*)&Pl[row * 136 + kc * 8];
    }
}

// ---- update GEMM (IN-PLACE safe: rev=e^1 stays in this block's tile) ------
__global__ __launch_bounds__(256, 3) void k_update(
    uint16_t* __restrict__ h_io, const float* __restrict__ sum,
    const int* __restrict__ srcv, const uint16_t* __restrict__ Wu,
    const float* __restrict__ b_upd) {
    __shared__ __align__(16) uint16_t A[128 * 136];
    __shared__ int src_lds[128];
    const int t = threadIdx.x;
    const int base = blockIdx.x * 128;
    if (t < 128) src_lds[t] = srcv[base + t];
    const int w = t >> 6, lane = t & 63;
    const int wm = w >> 1, wn = w & 1;
    const int l15 = lane & 15, q = lane >> 4;
    f32x4 acc[4][4];
    const f32x4 z = {0.f, 0.f, 0.f, 0.f};
    for (int i = 0; i < 4; ++i)
        for (int jj = 0; jj < 4; ++jj) acc[i][jj] = z;
    for (int j = 0; j < 8; ++j) {
        int c = j * 256 + t;
        int row = c >> 4, kc = c & 15;
        *(bf16x8*)&A[row * 136 + kc * 8] =
            *(const bf16x8*)(h_io + (size_t)(base + row) * H + kc * 8);
    }
    __syncthreads();
#pragma unroll
    for (int ks = 0; ks < 4; ++ks) {
        const int kk = ks * 32 + q * 8;
        bf16x8 a[4], b[4];
#pragma unroll
        for (int i = 0; i < 4; ++i)
            a[i] = *(const bf16x8*)&A[(wm * 64 + i * 16 + l15) * 136 + kk];
#pragma unroll
        for (int jj = 0; jj < 4; ++jj)
            b[jj] = *(const bf16x8*)&Wu[(wn * 64 + jj * 16 + l15) * KU + kk];
#pragma unroll
        for (int i = 0; i < 4; ++i)
#pragma unroll
            for (int jj = 0; jj < 4; ++jj)
                acc[i][jj] = __builtin_amdgcn_mfma_f32_16x16x32_bf16(a[i], b[jj], acc[i][jj], 0, 0, 0);
    }
    __syncthreads();
    for (int j = 0; j < 16; ++j) {
        int c4 = j * 256 + t;
        int row = c4 >> 5, cc = (c4 & 31) * 4;
        float4 s4 = *(const float4*)(sum + (size_t)src_lds[row] * H + cc);
        uint2 hv = *(const uint2*)(h_io + (size_t)(base + (row ^ 1)) * H + cc);
        float m0 = s4.x - bf2f((uint16_t)(hv.x & 0xFFFFu));
        float m1 = s4.y - bf2f((uint16_t)(hv.x >> 16));
        float m2 = s4.z - bf2f((uint16_t)(hv.y & 0xFFFFu));
        float m3 = s4.w - bf2f((uint16_t)(hv.y >> 16));
        uint2 p;
        p.x = (uint32_t)f2bf(m0) | ((uint32_t)f2bf(m1) << 16);
        p.y = (uint32_t)f2bf(m2) | ((uint32_t)f2bf(m3) << 16);
        *(uint2*)&A[row * 136 + cc] = p;
    }
    __syncthreads();
#pragma unroll
    for (int ks = 0; ks < 4; ++ks) {
        const int kk = ks * 32 + q * 8;
        bf16x8 a[4], b[4];
#pragma unroll
        for (int i = 0; i < 4; ++i)
            a[i] = *(const bf16x8*)&A[(wm * 64 + i * 16 + l15) * 136 + kk];
#pragma unroll
        for (int jj = 0; jj < 4; ++jj)
            b[jj] = *(const bf16x8*)&Wu[(wn * 64 + jj * 16 + l15) * KU + 128 + kk];
#pragma unroll
        for (int i = 0; i < 4; ++i)
#pragma unroll
            for (int jj = 0; jj < 4; ++jj)
                acc[i][jj] = __builtin_amdgcn_mfma_f32_16x16x32_bf16(a[i], b[jj], acc[i][jj], 0, 0, 0);
    }
    __syncthreads();
#pragma unroll
    for (int jj = 0; jj < 4; ++jj) {
        const int col = wn * 64 + jj * 16 + l15;
        const float bias = b_upd[col];
#pragma unroll
        for (int i = 0; i < 4; ++i)
#pragma unroll
            for (int r = 0; r < 4; ++r) {
                const int row = wm * 64 + i * 16 + q * 4 + r;
                float v = acc[i][jj][r] + bias;
                A[row * 136 + col] = f2bf(v > 0.f ? v : 0.f);
            }
    }
    __syncthreads();
    for (int j = 0; j < 8; ++j) {
        int c = j * 256 + t;
        int row = c >> 4, kc = c & 15;
        *(bf16x8*)(h_io + (size_t)(base + row) * H + kc * 8) =
            *(const bf16x8*)&A[row * 136 + kc * 8];
    }
}

// ---------------- readout: out += colsum(relu(sum @ Wr^T + b)) -------------
__global__ __launch_bounds__(256, 3) void k_readout(
    const float* __restrict__ sum, const uint16_t* __restrict__ Wr,
    const float* __restrict__ b_read, float* __restrict__ out) {
    __shared__ __align__(16) uint16_t A[128 * 136];
    __shared__ float col_lds[128];
    const int t = threadIdx.x;
    const int base = blockIdx.x * 128;
    if (t < 128) col_lds[t] = 0.f;
    for (int j = 0; j < 16; ++j) {
        int c4 = j * 256 + t;
        int row = c4 >> 5, cc = (c4 & 31) * 4;
        int a_idx = base + row;
        float4 s4 = make_float4(0.f, 0.f, 0.f, 0.f);
        if (a_idx < N_ATOMS) s4 = *(const float4*)(sum + (size_t)a_idx * H + cc);
        uint2 p;
        p.x = (uint32_t)f2bf(s4.x) | ((uint32_t)f2bf(s4.y) << 16);
        p.y = (uint32_t)f2bf(s4.z) | ((uint32_t)f2bf(s4.w) << 16);
        *(uint2*)&A[row * 136 + cc] = p;
    }
    __syncthreads();
    const int w = t >> 6, lane = t & 63;
    const int wm = w >> 1, wn = w & 1;
    const int l15 = lane & 15, q = lane >> 4;
    f32x4 acc[4][4];
    const f32x4 z = {0.f, 0.f, 0.f, 0.f};
    for (int i = 0; i < 4; ++i)
        for (int jj = 0; jj < 4; ++jj) acc[i][jj] = z;
#pragma unroll
    for (int ks = 0; ks < 4; ++ks) {
        const int kk = ks * 32 + q * 8;
        bf16x8 a[4], b[4];
#pragma unroll
        for (int i = 0; i < 4; ++i)
            a[i] = *(const bf16x8*)&A[(wm * 64 + i * 16 + l15) * 136 + kk];
#pragma unroll
        for (int jj = 0; jj < 4; ++jj)
            b[jj] = *(const bf16x8*)&Wr[(wn * 64 + jj * 16 + l15) * KR + kk];
#pragma unroll
        for (int i = 0; i < 4; ++i)
#pragma unroll
            for (int jj = 0; jj < 4; ++jj)
                acc[i][jj] = __builtin_amdgcn_mfma_f32_16x16x32_bf16(a[i], b[jj], acc[i][jj], 0, 0, 0);
    }
#pragma unroll
    for (int jj = 0; jj < 4; ++jj) {
        const int col = wn * 64 + jj * 16 + l15;
        const float bias = b_read[col];
        float s = 0.f;
#pragma unroll
        for (int i = 0; i < 4; ++i)
#pragma unroll
            for (int r = 0; r < 4; ++r) {
                const int a_idx = base + wm * 64 + i * 16 + q * 4 + r;
                if (a_idx < N_ATOMS) {
                    float v = acc[i][jj][r] + bias;
                    s += (v > 0.f) ? v : 0.f;
                }
            }
        atomicAdd(&col_lds[col], s);
    }
    __syncthreads();
    if (t < 128) atomicAdd(&out[t], col_lds[t]);
}

// ---------------- launch ---------------------------------------------------
extern "C" void kernel_launch(void* const* d_in, const int* in_sizes, int n_in,
                              void* d_out, int out_size, void* d_ws, size_t ws_size,
                              hipStream_t stream) {
    (void)in_sizes; (void)n_in; (void)out_size; (void)ws_size;
    const float* atom   = (const float*)d_in[0];
    const float* bond   = (const float*)d_in[1];
    const int* edge_idx = (const int*)d_in[2];
    const float* W_init = (const float*)d_in[3];
    const float* b_init = (const float*)d_in[4];
    const float* W_upd  = (const float*)d_in[5];
    const float* b_upd  = (const float*)d_in[6];
    const float* W_read = (const float*)d_in[7];
    const float* b_read = (const float*)d_in[8];
    float* out = (float*)d_out;

    char* ws = (char*)d_ws;
    // P aliases sum: P live only k_atom_gemm -> k_edge_init; sum written after.
    constexpr size_t SZ_H    = (size_t)N_EDGES * H * 2;            // 134217728
    constexpr size_t OFF_H   = 0;
    constexpr size_t OFF_SUM = OFF_H + SZ_H;
    constexpr size_t OFF_P   = OFF_SUM;                            // alias (12.8MB < 25.6MB)
    constexpr size_t OFF_WA  = OFF_SUM + (size_t)N_ATOMS * H * 4;
    constexpr size_t OFF_WB  = OFF_WA + (size_t)H * KI * 2;
    constexpr size_t OFF_WU  = OFF_WB + (size_t)H * KB * 2;
    constexpr size_t OFF_WR  = OFF_WU + (size_t)H * KU * 2;
    constexpr size_t OFF_CNT = OFF_WR + (size_t)H * KR * 2;
    constexpr size_t OFF_RP  = OFF_CNT + 200192;
    constexpr size_t OFF_NXT = OFF_RP + 200192;
    constexpr size_t OFF_ES  = OFF_NXT + 200192;

    uint16_t* h    = (uint16_t*)(ws + OFF_H);
    float* sum     = (float*)(ws + OFF_SUM);
    uint16_t* P    = (uint16_t*)(ws + OFF_P);
    uint16_t* Wa   = (uint16_t*)(ws + OFF_WA);
    uint16_t* Wb   = (uint16_t*)(ws + OFF_WB);
    uint16_t* Wu   = (uint16_t*)(ws + OFF_WU);
    uint16_t* Wr   = (uint16_t*)(ws + OFF_WR);
    int* counts    = (int*)(ws + OFF_CNT);
    int* row_ptr   = (int*)(ws + OFF_RP);
    int* nxt       = (int*)(ws + OFF_NXT);
    int* edge_slot = (int*)(ws + OFF_ES);

    const int* srcv = edge_idx;
    const int* dstv = edge_idx + N_EDGES;

    hipMemsetAsync(counts, 0, N_ATOMS * sizeof(int), stream);
    hipMemsetAsync(d_out, 0, H * sizeof(float), stream);

    k_weights<<<(H * KI + H * KB + H * KU + H * KR + 255) / 256, 256, 0, stream>>>(
        W_init, W_upd, W_read, Wa, Wb, Wu, Wr);
    k_hist<<<(N_EDGES + 255) / 256, 256, 0, stream>>>(dstv, counts);
    k_scan<<<1, 1024, 0, stream>>>(counts, row_ptr, nxt);
    k_scatter<<<(N_EDGES + 255) / 256, 256, 0, stream>>>(dstv, nxt, edge_slot);

    k_atom_gemm<<<(N_ATOMS + 127) / 128, 256, 0, stream>>>(atom, Wa, P);
    k_edge_init<<<N_EDGES / 128, 256, 0, stream>>>(bond, srcv, Wb, P, b_init, h);

    for (int d = 0; d < DEPTH; ++d) {
        k_segsum<<<(N_ATOMS + 3) / 4, 256, 0, stream>>>(h, row_ptr, edge_slot, sum);
        k_update<<<N_EDGES / 128, 256, 0, stream>>>(h, sum, srcv, Wu, b_upd);
    }
    k_segsum<<<(N_ATOMS + 3) / 4, 256, 0, stream>>>(h, row_ptr, edge_slot, sum);
    k_readout<<<(N_ATOMS + 127) / 128, 256, 0, stream>>>(sum, Wr, b_read, out);
}

// Round 4
// 836.850 us; speedup vs baseline: 1.4353x; 1.1288x over previous
//
#include <hip/hip_runtime.h>
#include <stdint.h>
#include <stddef.h>

#define N_ATOMS 50000
#define N_EDGES 524288
#define FA 133
#define FB 14
#define H 128
#define DEPTH 3
#define KI 160   /* 133 padded to multiple of 32 */
#define KB 32    /* 14 padded to 32 */
#define KU 256
#define KR 128

typedef __attribute__((ext_vector_type(8))) __bf16 bf16x8;
typedef __attribute__((ext_vector_type(4))) float f32x4;

__device__ __forceinline__ uint16_t f2bf(float f) {
    uint32_t u = __builtin_bit_cast(uint32_t, f);
    return (uint16_t)((u + 0x7FFFu + ((u >> 16) & 1u)) >> 16);
}
__device__ __forceinline__ float bf2f(uint16_t h) {
    return __builtin_bit_cast(float, (uint32_t)h << 16);
}

// ---- weight conversion: Wa = Wi[:, :133] pad->160, Wb = Wi[:, 133:147] pad->32
__global__ void k_weights(const float* __restrict__ Wi_f,
                          const float* __restrict__ Wu_f,
                          const float* __restrict__ Wr_f,
                          uint16_t* __restrict__ Wa,
                          uint16_t* __restrict__ Wb,
                          uint16_t* __restrict__ Wu,
                          uint16_t* __restrict__ Wr) {
    int i = blockIdx.x * 256 + threadIdx.x;
    if (i < H * KI) {
        int o = i / KI, k = i - o * KI;
        Wa[i] = f2bf((k < FA) ? Wi_f[o * (FA + FB) + k] : 0.f);
    } else if (i < H * KI + H * KB) {
        int j = i - H * KI;
        int o = j >> 5, k = j & 31;
        Wb[j] = f2bf((k < FB) ? Wi_f[o * (FA + FB) + FA + k] : 0.f);
    } else if (i < H * KI + H * KB + H * KU) {
        int j = i - H * KI - H * KB;
        Wu[j] = f2bf(Wu_f[j]);
    } else if (i < H * KI + H * KB + H * KU + H * KR) {
        int j = i - H * KI - H * KB - H * KU;
        Wr[j] = f2bf(Wr_f[j]);
    }
}

// ---------------- CSR build ------------------------------------------------
__global__ void k_hist(const int* __restrict__ dstv, int* __restrict__ counts) {
    int e = blockIdx.x * 256 + threadIdx.x;
    if (e < N_EDGES) atomicAdd(&counts[dstv[e]], 1);
}

__global__ void k_scan(const int* __restrict__ counts,
                       int* __restrict__ row_ptr, int* __restrict__ nxt) {
    __shared__ int s[1024];
    const int t = threadIdx.x;
    const int PER = (N_ATOMS + 1023) / 1024;  // 49
    const int base = t * PER;
    int local = 0;
    for (int j = 0; j < PER; ++j) {
        int i = base + j;
        if (i < N_ATOMS) local += counts[i];
    }
    s[t] = local;
    __syncthreads();
    for (int off = 1; off < 1024; off <<= 1) {
        int u = (t >= off) ? s[t - off] : 0;
        __syncthreads();
        s[t] += u;
        __syncthreads();
    }
    int run = s[t] - local;
    for (int j = 0; j < PER; ++j) {
        int i = base + j;
        if (i < N_ATOMS) {
            row_ptr[i] = run;
            nxt[i] = run;
            run += counts[i];
        }
    }
    if (t == 1023) row_ptr[N_ATOMS] = run;
}

__global__ void k_scatter(const int* __restrict__ dstv, int* __restrict__ nxt,
                          int* __restrict__ edge_slot) {
    int e = blockIdx.x * 256 + threadIdx.x;
    if (e < N_EDGES) {
        int pos = atomicAdd(&nxt[dstv[e]], 1);
        edge_slot[pos] = e;
    }
}

// ---- segment sum -> bf16 table. Quarter-wave (16 lanes) per atom,
// 16 B/lane full-row loads, 2 rows in flight + edge-id prefetch. ------------
__global__ void k_segsum(const uint16_t* __restrict__ h,
                         const int* __restrict__ row_ptr,
                         const int* __restrict__ edge_slot,
                         uint16_t* __restrict__ sumbf) {
    const int qw = threadIdx.x >> 4;   // 16 quarters per block
    const int ql = threadIdx.x & 15;
    const int a = blockIdx.x * 16 + qw;  // N_ATOMS = 3125*16 exactly
    const int s0 = row_ptr[a], s1 = row_ptr[a + 1];
    float acc[8];
#pragma unroll
    for (int i = 0; i < 8; ++i) acc[i] = 0.f;
    int p = s0;
    int eA = (p < s1) ? edge_slot[p] : 0;
    int eB = (p + 1 < s1) ? edge_slot[p + 1] : 0;
    while (p < s1) {
        const bool hasB = (p + 1 < s1);
        const bf16x8 vA = *(const bf16x8*)(h + (size_t)eA * H + ql * 8);
        bf16x8 vB;
        if (hasB) vB = *(const bf16x8*)(h + (size_t)eB * H + ql * 8);
        const int np = p + 2;
        eA = (np < s1) ? edge_slot[np] : 0;
        eB = (np + 1 < s1) ? edge_slot[np + 1] : 0;
#pragma unroll
        for (int i = 0; i < 8; ++i) acc[i] += (float)vA[i];
        if (hasB) {
#pragma unroll
            for (int i = 0; i < 8; ++i) acc[i] += (float)vB[i];
        }
        p = np;
    }
    uint4 o;
    o.x = (uint32_t)f2bf(acc[0]) | ((uint32_t)f2bf(acc[1]) << 16);
    o.y = (uint32_t)f2bf(acc[2]) | ((uint32_t)f2bf(acc[3]) << 16);
    o.z = (uint32_t)f2bf(acc[4]) | ((uint32_t)f2bf(acc[5]) << 16);
    o.w = (uint32_t)f2bf(acc[6]) | ((uint32_t)f2bf(acc[7]) << 16);
    *(uint4*)(sumbf + (size_t)a * H + ql * 8) = o;
}

// ---- P = atom @ Wa^T (dense, gather-free; M=50048 in 391 tiles) -----------
__global__ __launch_bounds__(256, 3) void k_atom_gemm(
    const float* __restrict__ atom, const uint16_t* __restrict__ Wa,
    uint16_t* __restrict__ P) {
    __shared__ __align__(16) uint16_t A[128 * 168];
    const int t = threadIdx.x;
    const int base = blockIdx.x * 128;
    if (t < 128) {
        for (int c = FA; c < KI; ++c) A[t * 168 + c] = 0;
    }
    for (int j = 0; j < 67; ++j) {
        int f = j * 256 + t;
        if (f < 128 * FA) {
            int row = f / FA, col = f - row * FA;
            int a = base + row;
            float v = (a < N_ATOMS) ? atom[(size_t)a * FA + col] : 0.f;
            A[row * 168 + col] = f2bf(v);
        }
    }
    __syncthreads();
    const int w = t >> 6, lane = t & 63;
    const int wm = w >> 1, wn = w & 1;
    const int l15 = lane & 15, q = lane >> 4;
    f32x4 acc[4][4];
    const f32x4 z = {0.f, 0.f, 0.f, 0.f};
    for (int i = 0; i < 4; ++i)
        for (int jj = 0; jj < 4; ++jj) acc[i][jj] = z;
#pragma unroll
    for (int ks = 0; ks < 5; ++ks) {
        const int kk = ks * 32 + q * 8;
        bf16x8 a[4], b[4];
#pragma unroll
        for (int i = 0; i < 4; ++i)
            a[i] = *(const bf16x8*)&A[(wm * 64 + i * 16 + l15) * 168 + kk];
#pragma unroll
        for (int jj = 0; jj < 4; ++jj)
            b[jj] = *(const bf16x8*)&Wa[(wn * 64 + jj * 16 + l15) * KI + kk];
#pragma unroll
        for (int i = 0; i < 4; ++i)
#pragma unroll
            for (int jj = 0; jj < 4; ++jj)
                acc[i][jj] = __builtin_amdgcn_mfma_f32_16x16x32_bf16(a[i], b[jj], acc[i][jj], 0, 0, 0);
    }
    __syncthreads();
#pragma unroll
    for (int jj = 0; jj < 4; ++jj) {
        const int col = wn * 64 + jj * 16 + l15;
#pragma unroll
        for (int i = 0; i < 4; ++i)
#pragma unroll
            for (int r = 0; r < 4; ++r) {
                const int row = wm * 64 + i * 16 + q * 4 + r;
                A[row * 136 + col] = f2bf(acc[i][jj][r]);
            }
    }
    __syncthreads();
    for (int j = 0; j < 8; ++j) {
        int c = j * 256 + t;
        int row = c >> 4, kc = c & 15;
        *(bf16x8*)(P + (size_t)(base + row) * H + kc * 8) =
            *(const bf16x8*)&A[row * 136 + kc * 8];
    }
}

// ---- h0 = relu(P[src] + bond @ Wb^T + b_init) -----------------------------
__global__ __launch_bounds__(256, 3) void k_edge_init(
    const float* __restrict__ bond, const int* __restrict__ srcv,
    const uint16_t* __restrict__ Wb, const uint16_t* __restrict__ P,
    const float* __restrict__ b_init, uint16_t* __restrict__ h_out) {
    __shared__ __align__(16) uint16_t Pl[128 * 136];
    __shared__ __align__(16) uint16_t Bb[128 * 40];
    __shared__ int src_lds[128];
    const int t = threadIdx.x;
    const int base = blockIdx.x * 128;
    if (t < 128) {
        src_lds[t] = srcv[base + t];
        for (int c = FB; c < KB; ++c) Bb[t * 40 + c] = 0;
    }
    for (int j = 0; j < 7; ++j) {
        int f = j * 256 + t;  // f < 1792 always
        int row = f / FB, col = f - row * FB;
        Bb[row * 40 + col] = f2bf(bond[(size_t)(base + row) * FB + col]);
    }
    __syncthreads();
    for (int j = 0; j < 8; ++j) {
        int task = j * 256 + t;
        int row = task >> 4, seg = task & 15;
        *(bf16x8*)&Pl[row * 136 + seg * 8] =
            *(const bf16x8*)(P + (size_t)src_lds[row] * H + seg * 8);
    }
    const int w = t >> 6, lane = t & 63;
    const int wm = w >> 1, wn = w & 1;
    const int l15 = lane & 15, q = lane >> 4;
    f32x4 acc[4][4];
    const f32x4 z = {0.f, 0.f, 0.f, 0.f};
    for (int i = 0; i < 4; ++i)
        for (int jj = 0; jj < 4; ++jj) acc[i][jj] = z;
    {
        const int kk = q * 8;
        bf16x8 a[4], b[4];
#pragma unroll
        for (int i = 0; i < 4; ++i)
            a[i] = *(const bf16x8*)&Bb[(wm * 64 + i * 16 + l15) * 40 + kk];
#pragma unroll
        for (int jj = 0; jj < 4; ++jj)
            b[jj] = *(const bf16x8*)&Wb[(wn * 64 + jj * 16 + l15) * KB + kk];
#pragma unroll
        for (int i = 0; i < 4; ++i)
#pragma unroll
            for (int jj = 0; jj < 4; ++jj)
                acc[i][jj] = __builtin_amdgcn_mfma_f32_16x16x32_bf16(a[i], b[jj], acc[i][jj], 0, 0, 0);
    }
    __syncthreads();  // Pl gather complete
#pragma unroll
    for (int jj = 0; jj < 4; ++jj) {
        const int col = wn * 64 + jj * 16 + l15;
        const float bias = b_init[col];
#pragma unroll
        for (int i = 0; i < 4; ++i)
#pragma unroll
            for (int r = 0; r < 4; ++r) {
                const int row = wm * 64 + i * 16 + q * 4 + r;
                float v = acc[i][jj][r] + bf2f(Pl[row * 136 + col]) + bias;
                Pl[row * 136 + col] = f2bf(v > 0.f ? v : 0.f);
            }
    }
    __syncthreads();
    for (int j = 0; j < 8; ++j) {
        int c = j * 256 + t;
        int row = c >> 4, kc = c & 15;
        *(bf16x8*)(h_out + (size_t)(base + row) * H + kc * 8) =
            *(const bf16x8*)&Pl[row * 136 + kc * 8];
    }
}

// ---- update GEMM (IN-PLACE safe: rev=e^1 stays in this block's tile) ------
__global__ __launch_bounds__(256, 3) void k_update(
    uint16_t* __restrict__ h_io, const uint16_t* __restrict__ sumbf,
    const int* __restrict__ srcv, const uint16_t* __restrict__ Wu,
    const float* __restrict__ b_upd) {
    __shared__ __align__(16) uint16_t A[128 * 136];
    __shared__ int src_lds[128];
    const int t = threadIdx.x;
    const int base = blockIdx.x * 128;
    if (t < 128) src_lds[t] = srcv[base + t];
    const int w = t >> 6, lane = t & 63;
    const int wm = w >> 1, wn = w & 1;
    const int l15 = lane & 15, q = lane >> 4;
    f32x4 acc[4][4];
    const f32x4 z = {0.f, 0.f, 0.f, 0.f};
    for (int i = 0; i < 4; ++i)
        for (int jj = 0; jj < 4; ++jj) acc[i][jj] = z;
    for (int j = 0; j < 8; ++j) {
        int c = j * 256 + t;
        int row = c >> 4, kc = c & 15;
        *(bf16x8*)&A[row * 136 + kc * 8] =
            *(const bf16x8*)(h_io + (size_t)(base + row) * H + kc * 8);
    }
    __syncthreads();
#pragma unroll
    for (int ks = 0; ks < 4; ++ks) {
        const int kk = ks * 32 + q * 8;
        bf16x8 a[4], b[4];
#pragma unroll
        for (int i = 0; i < 4; ++i)
            a[i] = *(const bf16x8*)&A[(wm * 64 + i * 16 + l15) * 136 + kk];
#pragma unroll
        for (int jj = 0; jj < 4; ++jj)
            b[jj] = *(const bf16x8*)&Wu[(wn * 64 + jj * 16 + l15) * KU + kk];
#pragma unroll
        for (int i = 0; i < 4; ++i)
#pragma unroll
            for (int jj = 0; jj < 4; ++jj)
                acc[i][jj] = __builtin_amdgcn_mfma_f32_16x16x32_bf16(a[i], b[jj], acc[i][jj], 0, 0, 0);
    }
    __syncthreads();
    // phase 1: k=128..255 is m = sum_bf16[src[e]] - h[e^1]; 16 B/lane loads
    for (int j = 0; j < 8; ++j) {
        int c = j * 256 + t;
        int row = c >> 4, seg = c & 15;
        const bf16x8 sv = *(const bf16x8*)(sumbf + (size_t)src_lds[row] * H + seg * 8);
        const bf16x8 hv = *(const bf16x8*)(h_io + (size_t)(base + (row ^ 1)) * H + seg * 8);
        float m0 = (float)sv[0] - (float)hv[0];
        float m1 = (float)sv[1] - (float)hv[1];
        float m2 = (float)sv[2] - (float)hv[2];
        float m3 = (float)sv[3] - (float)hv[3];
        float m4 = (float)sv[4] - (float)hv[4];
        float m5 = (float)sv[5] - (float)hv[5];
        float m6 = (float)sv[6] - (float)hv[6];
        float m7 = (float)sv[7] - (float)hv[7];
        uint4 pck;
        pck.x = (uint32_t)f2bf(m0) | ((uint32_t)f2bf(m1) << 16);
        pck.y = (uint32_t)f2bf(m2) | ((uint32_t)f2bf(m3) << 16);
        pck.z = (uint32_t)f2bf(m4) | ((uint32_t)f2bf(m5) << 16);
        pck.w = (uint32_t)f2bf(m6) | ((uint32_t)f2bf(m7) << 16);
        *(uint4*)&A[row * 136 + seg * 8] = pck;
    }
    __syncthreads();
#pragma unroll
    for (int ks = 0; ks < 4; ++ks) {
        const int kk = ks * 32 + q * 8;
        bf16x8 a[4], b[4];
#pragma unroll
        for (int i = 0; i < 4; ++i)
            a[i] = *(const bf16x8*)&A[(wm * 64 + i * 16 + l15) * 136 + kk];
#pragma unroll
        for (int jj = 0; jj < 4; ++jj)
            b[jj] = *(const bf16x8*)&Wu[(wn * 64 + jj * 16 + l15) * KU + 128 + kk];
#pragma unroll
        for (int i = 0; i < 4; ++i)
#pragma unroll
            for (int jj = 0; jj < 4; ++jj)
                acc[i][jj] = __builtin_amdgcn_mfma_f32_16x16x32_bf16(a[i], b[jj], acc[i][jj], 0, 0, 0);
    }
    __syncthreads();
#pragma unroll
    for (int jj = 0; jj < 4; ++jj) {
        const int col = wn * 64 + jj * 16 + l15;
        const float bias = b_upd[col];
#pragma unroll
        for (int i = 0; i < 4; ++i)
#pragma unroll
            for (int r = 0; r < 4; ++r) {
                const int row = wm * 64 + i * 16 + q * 4 + r;
                float v = acc[i][jj][r] + bias;
                A[row * 136 + col] = f2bf(v > 0.f ? v : 0.f);
            }
    }
    __syncthreads();
    for (int j = 0; j < 8; ++j) {
        int c = j * 256 + t;
        int row = c >> 4, kc = c & 15;
        *(bf16x8*)(h_io + (size_t)(base + row) * H + kc * 8) =
            *(const bf16x8*)&A[row * 136 + kc * 8];
    }
}

// ---------------- readout: out += colsum(relu(sumbf @ Wr^T + b)) -----------
__global__ __launch_bounds__(256, 3) void k_readout(
    const uint16_t* __restrict__ sumbf, const uint16_t* __restrict__ Wr,
    const float* __restrict__ b_read, float* __restrict__ out) {
    __shared__ __align__(16) uint16_t A[128 * 136];
    __shared__ float col_lds[128];
    const int t = threadIdx.x;
    const int base = blockIdx.x * 128;
    if (t < 128) col_lds[t] = 0.f;
    for (int j = 0; j < 8; ++j) {
        int c = j * 256 + t;
        int row = c >> 4, seg = c & 15;
        int a_idx = base + row;
        uint4 v = make_uint4(0u, 0u, 0u, 0u);
        if (a_idx < N_ATOMS)
            v = *(const uint4*)(sumbf + (size_t)a_idx * H + seg * 8);
        *(uint4*)&A[row * 136 + seg * 8] = v;
    }
    __syncthreads();
    const int w = t >> 6, lane = t & 63;
    const int wm = w >> 1, wn = w & 1;
    const int l15 = lane & 15, q = lane >> 4;
    f32x4 acc[4][4];
    const f32x4 z = {0.f, 0.f, 0.f, 0.f};
    for (int i = 0; i < 4; ++i)
        for (int jj = 0; jj < 4; ++jj) acc[i][jj] = z;
#pragma unroll
    for (int ks = 0; ks < 4; ++ks) {
        const int kk = ks * 32 + q * 8;
        bf16x8 a[4], b[4];
#pragma unroll
        for (int i = 0; i < 4; ++i)
            a[i] = *(const bf16x8*)&A[(wm * 64 + i * 16 + l15) * 136 + kk];
#pragma unroll
        for (int jj = 0; jj < 4; ++jj)
            b[jj] = *(const bf16x8*)&Wr[(wn * 64 + jj * 16 + l15) * KR + kk];
#pragma unroll
        for (int i = 0; i < 4; ++i)
#pragma unroll
            for (int jj = 0; jj < 4; ++jj)
                acc[i][jj] = __builtin_amdgcn_mfma_f32_16x16x32_bf16(a[i], b[jj], acc[i][jj], 0, 0, 0);
    }
#pragma unroll
    for (int jj = 0; jj < 4; ++jj) {
        const int col = wn * 64 + jj * 16 + l15;
        const float bias = b_read[col];
        float s = 0.f;
#pragma unroll
        for (int i = 0; i < 4; ++i)
#pragma unroll
            for (int r = 0; r < 4; ++r) {
                const int a_idx = base + wm * 64 + i * 16 + q * 4 + r;
                if (a_idx < N_ATOMS) {
                    float v = acc[i][jj][r] + bias;
                    s += (v > 0.f) ? v : 0.f;
                }
            }
        atomicAdd(&col_lds[col], s);
    }
    __syncthreads();
    if (t < 128) atomicAdd(&out[t], col_lds[t]);
}

// ---------------- launch ---------------------------------------------------
extern "C" void kernel_launch(void* const* d_in, const int* in_sizes, int n_in,
                              void* d_out, int out_size, void* d_ws, size_t ws_size,
                              hipStream_t stream) {
    (void)in_sizes; (void)n_in; (void)out_size; (void)ws_size;
    const float* atom   = (const float*)d_in[0];
    const float* bond   = (const float*)d_in[1];
    const int* edge_idx = (const int*)d_in[2];
    const float* W_init = (const float*)d_in[3];
    const float* b_init = (const float*)d_in[4];
    const float* W_upd  = (const float*)d_in[5];
    const float* b_upd  = (const float*)d_in[6];
    const float* W_read = (const float*)d_in[7];
    const float* b_read = (const float*)d_in[8];
    float* out = (float*)d_out;

    char* ws = (char*)d_ws;
    // sumbf (bf16, 12.8 MB) aliases P (bf16, 12.8 MB): P live only
    // k_atom_gemm -> k_edge_init; sumbf written after k_edge_init.
    constexpr size_t SZ_H    = (size_t)N_EDGES * H * 2;            // 134217728
    constexpr size_t OFF_H   = 0;
    constexpr size_t OFF_SUM = OFF_H + SZ_H;
    constexpr size_t OFF_P   = OFF_SUM;
    constexpr size_t OFF_WA  = OFF_SUM + (size_t)N_ATOMS * H * 4;
    constexpr size_t OFF_WB  = OFF_WA + (size_t)H * KI * 2;
    constexpr size_t OFF_WU  = OFF_WB + (size_t)H * KB * 2;
    constexpr size_t OFF_WR  = OFF_WU + (size_t)H * KU * 2;
    constexpr size_t OFF_CNT = OFF_WR + (size_t)H * KR * 2;
    constexpr size_t OFF_RP  = OFF_CNT + 200192;
    constexpr size_t OFF_NXT = OFF_RP + 200192;
    constexpr size_t OFF_ES  = OFF_NXT + 200192;

    uint16_t* h     = (uint16_t*)(ws + OFF_H);
    uint16_t* sumbf = (uint16_t*)(ws + OFF_SUM);
    uint16_t* P     = (uint16_t*)(ws + OFF_P);
    uint16_t* Wa    = (uint16_t*)(ws + OFF_WA);
    uint16_t* Wb    = (uint16_t*)(ws + OFF_WB);
    uint16_t* Wu    = (uint16_t*)(ws + OFF_WU);
    uint16_t* Wr    = (uint16_t*)(ws + OFF_WR);
    int* counts     = (int*)(ws + OFF_CNT);
    int* row_ptr    = (int*)(ws + OFF_RP);
    int* nxt        = (int*)(ws + OFF_NXT);
    int* edge_slot  = (int*)(ws + OFF_ES);

    const int* srcv = edge_idx;
    const int* dstv = edge_idx + N_EDGES;

    hipMemsetAsync(counts, 0, N_ATOMS * sizeof(int), stream);
    hipMemsetAsync(d_out, 0, H * sizeof(float), stream);

    k_weights<<<(H * KI + H * KB + H * KU + H * KR + 255) / 256, 256, 0, stream>>>(
        W_init, W_upd, W_read, Wa, Wb, Wu, Wr);
    k_hist<<<(N_EDGES + 255) / 256, 256, 0, stream>>>(dstv, counts);
    k_scan<<<1, 1024, 0, stream>>>(counts, row_ptr, nxt);
    k_scatter<<<(N_EDGES + 255) / 256, 256, 0, stream>>>(dstv, nxt, edge_slot);

    k_atom_gemm<<<(N_ATOMS + 127) / 128, 256, 0, stream>>>(atom, Wa, P);
    k_edge_init<<<N_EDGES / 128, 256, 0, stream>>>(bond, srcv, Wb, P, b_init, h);

    for (int d = 0; d < DEPTH; ++d) {
        k_segsum<<<N_ATOMS / 16, 256, 0, stream>>>(h, row_ptr, edge_slot, sumbf);
        k_update<<<N_EDGES / 128, 256, 0, stream>>>(h, sumbf, srcv, Wu, b_upd);
    }
    k_segsum<<<N_ATOMS / 16, 256, 0, stream>>>(h, row_ptr, edge_slot, sumbf);
    k_readout<<<(N_ATOMS + 127) / 128, 256, 0, stream>>>(sumbf, Wr, b_read, out);
}